// Round 7
// baseline (125.455 us; speedup 1.0000x reference)
//
#include <hip/hip_runtime.h>
#include <hip/hip_fp16.h>

// ---------------------------------------------------------------------------
// TwoLayerGAT: CSR gather + MFMA fp16 GEMM, 6-launch pipeline.
//   prep_wt      : W1/W2 -> fp16 transposed; zeroes per-bucket totals.
//   fused_bin_g1 : blocks [0,NBIN) block-local LDS bucket-sort of their edge
//                  range, flushed LINEARLY to a block-exclusive region
//                  (no global cursors, no cross-XCD line sharing);
//                  blocks [NBIN,..) layer-1 MFMA GEMM + fused s/d scores.
//   build_csr    : per bucket: gather the NBIN per-block sub-runs (bounds
//                  cached in LDS), build CSR segment in LDS, flush coalesced.
//   gat_gather   : per-dst fused softmax-aggregate (8-deep predicated MLP).
//   gemm2, gather2 as layer 2.
// Softmax max-subtraction omitted (logits bounded, exp safe in fp32).
// ---------------------------------------------------------------------------

typedef _Float16 half8 __attribute__((ext_vector_type(8)));
typedef float f32x4 __attribute__((ext_vector_type(4)));

constexpr int BCAP = 8192;   // per-bucket CSR-segment capacity (avg ~4330)
constexpr int NTHB = 256;    // nodes per bucket (dst>>8)
constexpr int NBIN = 128;    // binning blocks (block-exclusive regions)

// Wt1[c][k] = W1[k][c] (fp16), Wt2 likewise; tail zeroes gtot.
__global__ __launch_bounds__(256) void prep_wt(const float* __restrict__ W1,
                                               const float* __restrict__ W2,
                                               _Float16* __restrict__ Wt1,
                                               _Float16* __restrict__ Wt2,
                                               int* __restrict__ gtot) {
    int i = blockIdx.x * blockDim.x + threadIdx.x;
    if (i < 128 * 128) {
        int c = i >> 7, k = i & 127;
        Wt1[i] = (_Float16)W1[k * 128 + c];
    } else if (i < 128 * 128 + 64 * 128) {
        int j = i - 128 * 128;
        int c = j >> 7, k = j & 127;
        Wt2[j] = (_Float16)W2[k * 64 + c];
    } else if (i < 128 * 128 + 64 * 128 + 256) {
        gtot[i - (128 * 128 + 64 * 128)] = 0;
    }
}

// Fused: blocks [0,NBIN) = block-local bucket sort; rest = layer-1 GEMM.
// MFMA 16x16x32 f16: A lane l: row=l&15, k=(l>>4)*8+j (contig);
//                    B lane l: col=l&15, same k (contig in Wt[col][k]);
//                    D lane l reg r: row=(l>>4)*4+r, col=l&15.
__global__ __launch_bounds__(256) void fused_bin_gemm1(
        const int* __restrict__ ei, int* __restrict__ gtot,
        int* __restrict__ offs, unsigned int* __restrict__ packed,
        int E, int nb, int Epb,
        const float* __restrict__ X, const _Float16* __restrict__ Wt,
        const float* __restrict__ a_src, const float* __restrict__ a_dst,
        _Float16* __restrict__ Yh, float* __restrict__ s,
        float* __restrict__ d, int N) {
    // binning: cnt[256] + scn[256] + staged[Epb]  = 2048 + 25000 = 27048 B
    // gemm   : xs[64][136] fp16                   = 17408 B
    __shared__ __align__(16) char smem[27056];
    const int tid = threadIdx.x;

    if (blockIdx.x < NBIN) {
        // ---------------- block-local LDS bucket sort ----------------
        int* cnt = (int*)smem;                       // histogram, then cursor
        int* scn = cnt + 256;
        unsigned int* staged = (unsigned int*)(scn + 256);
        const int blk = blockIdx.x;
        const int e0  = blk * Epb;
        int ecnt = E - e0; ecnt = ecnt < 0 ? 0 : (ecnt > Epb ? Epb : ecnt);

        cnt[tid] = 0;
        __syncthreads();
        for (int k = tid; k < ecnt; k += 256)
            atomicAdd(&cnt[ei[E + e0 + k] >> 8], 1);
        __syncthreads();

        int v = cnt[tid];
        scn[tid] = v;
        __syncthreads();
        for (int off = 1; off < 256; off <<= 1) {
            int t = (tid >= off) ? scn[tid - off] : 0;
            __syncthreads();
            scn[tid] += t;
            __syncthreads();
        }
        const int sbase = scn[tid] - v;              // exclusive prefix
        if (tid < nb + 1) offs[blk * (nb + 1) + tid] = sbase;  // [nb] = total
        if (tid < nb && v) atomicAdd(&gtot[tid], v);
        cnt[tid] = sbase;                            // cursor
        __syncthreads();

        for (int k = tid; k < ecnt; k += 256) {
            int src = ei[e0 + k], dst = ei[E + e0 + k];
            int pos = atomicAdd(&cnt[dst >> 8], 1);
            staged[pos] = ((unsigned)(dst & 255) << 16) | (unsigned)src;
        }
        __syncthreads();

        unsigned int* dstp = &packed[(size_t)blk * Epb];
        for (int k = tid; k < ecnt; k += 256)        // linear, block-exclusive
            dstp[k] = staged[k];
        return;
    }

    // ---------------- layer-1 GEMM + scores ----------------
    constexpr int H = 4, NT = 8, TPH = 2, FOUT = 128;
    auto xs = (_Float16(*)[136])smem;
    const int row0 = (blockIdx.x - NBIN) * 64;

    for (int c = tid; c < 2048; c += 256) {          // 64 rows x 32 float4
        int r = c >> 5, c4 = c & 31;
        float4 v = make_float4(0.f, 0.f, 0.f, 0.f);
        if (row0 + r < N)
            v = reinterpret_cast<const float4*>(X)[(size_t)(row0 + r) * 32 + c4];
        _Float16* p = &xs[r][c4 * 4];
        p[0] = (_Float16)v.x; p[1] = (_Float16)v.y;
        p[2] = (_Float16)v.z; p[3] = (_Float16)v.w;
    }
    __syncthreads();

    const int wid  = tid >> 6;
    const int lane = tid & 63;
    const int l15  = lane & 15;
    const int lg   = lane >> 4;

    f32x4 acc[NT];
    #pragma unroll
    for (int n = 0; n < NT; ++n) acc[n] = (f32x4){0.f, 0.f, 0.f, 0.f};

    const half8* WtV = reinterpret_cast<const half8*>(Wt);  // [FOUT][16] half8
    #pragma unroll
    for (int ks = 0; ks < 4; ++ks) {
        half8 a = *reinterpret_cast<const half8*>(&xs[wid * 16 + l15][ks * 32 + lg * 8]);
        #pragma unroll
        for (int n = 0; n < NT; ++n) {
            half8 b = WtV[(size_t)(n * 16 + l15) * 16 + ks * 4 + lg];
            acc[n] = __builtin_amdgcn_mfma_f32_16x16x32_f16(a, b, acc[n], 0, 0, 0);
        }
    }

    float av[NT], bv[NT];
    #pragma unroll
    for (int n = 0; n < NT; ++n) {
        av[n] = a_src[n * 16 + l15];
        bv[n] = a_dst[n * 16 + l15];
    }

    #pragma unroll
    for (int r = 0; r < 4; ++r) {
        int row = row0 + wid * 16 + lg * 4 + r;
        bool ok = row < N;
        if (ok) {
            #pragma unroll
            for (int n = 0; n < NT; ++n)
                Yh[(size_t)row * FOUT + n * 16 + l15] = (_Float16)acc[n][r];
        }
        #pragma unroll
        for (int h = 0; h < H; ++h) {
            float ls = 0.f, ld = 0.f;
            #pragma unroll
            for (int t = 0; t < TPH; ++t) {
                int n = h * TPH + t;
                ls = fmaf(acc[n][r], av[n], ls);
                ld = fmaf(acc[n][r], bv[n], ld);
            }
            #pragma unroll
            for (int m = 1; m < 16; m <<= 1) {
                ls += __shfl_xor(ls, m);
                ld += __shfl_xor(ld, m);
            }
            if (ok && l15 == h) {
                s[(size_t)row * H + h] = ls;
                d[(size_t)row * H + h] = ld;
            }
        }
    }
}

// One block per bucket: gather NBIN per-block sub-runs, CSR built in LDS.
__global__ __launch_bounds__(256) void build_csr(const unsigned int* __restrict__ packed,
                                                 const int* __restrict__ gtot,
                                                 const int* __restrict__ offs,
                                                 unsigned short* __restrict__ csr,
                                                 int* __restrict__ row_end,
                                                 int N, int nb, int Epb) {
    __shared__ int deg[256];
    __shared__ int scn[256];
    __shared__ int rst[NBIN], ren[NBIN];
    __shared__ unsigned short lcsr[BCAP + 256];
    const int b   = blockIdx.x;
    const int tid = threadIdx.x;
    const int node = (b << 8) + tid;
    const bool real = node < N;

    // global base: exclusive prefix of (bucket_edges + bucket_nodes) up to b
    int nodes_t = N - tid * NTHB;
    nodes_t = nodes_t < 0 ? 0 : (nodes_t > NTHB ? NTHB : nodes_t);
    int vall = (tid < nb) ? gtot[tid] + nodes_t : 0;
    scn[tid] = vall;
    __syncthreads();
    for (int off = 1; off < 256; off <<= 1) {
        int t = (tid >= off) ? scn[tid - off] : 0;
        __syncthreads();
        scn[tid] += t;
        __syncthreads();
    }
    int nodes_b = N - b * NTHB;
    nodes_b = nodes_b < 0 ? 0 : (nodes_b > NTHB ? NTHB : nodes_b);
    const int gb = scn[b] - gtot[b] - nodes_b;       // exclusive prefix
    __syncthreads();

    // cache per-bin-block run bounds for this bucket
    if (tid < NBIN) {
        rst[tid] = offs[tid * (nb + 1) + b];
        ren[tid] = offs[tid * (nb + 1) + b + 1];
    }
    deg[tid] = real ? 1 : 0;                 // self loop
    __syncthreads();

    const int wv = tid >> 6, ln = tid & 63;
    for (int i = wv; i < NBIN; i += 4) {
        const unsigned int* pk = &packed[(size_t)i * Epb];
        int st = rst[i], en = ren[i];
        for (int k = st + ln; k < en; k += 64)
            atomicAdd(&deg[pk[k] >> 16], 1);
    }
    __syncthreads();

    int v = deg[tid];
    scn[tid] = v;
    __syncthreads();
    for (int off = 1; off < 256; off <<= 1) {
        int t = (tid >= off) ? scn[tid - off] : 0;
        __syncthreads();
        scn[tid] += t;
        __syncthreads();
    }
    const int incl  = scn[tid];
    const int start = incl - v;
    const int tot   = scn[255];
    __syncthreads();

    if (real) {
        lcsr[start] = (unsigned short)node;  // self loop first
        row_end[node] = gb + incl;
    }
    deg[tid] = start + (real ? 1 : 0);       // cursor
    __syncthreads();

    for (int i = wv; i < NBIN; i += 4) {
        const unsigned int* pk = &packed[(size_t)i * Epb];
        int st = rst[i], en = ren[i];
        for (int k = st + ln; k < en; k += 64) {
            unsigned int p = pk[k];
            int pos = atomicAdd(&deg[p >> 16], 1);
            lcsr[pos] = (unsigned short)(p & 0xffffu);
        }
    }
    __syncthreads();

    for (int k = tid; k < tot; k += 256)
        csr[gb + k] = lcsr[k];
}

// Layer-2 GEMM (standalone), fp16 input.
__global__ __launch_bounds__(256) void gemm_score2(const _Float16* __restrict__ X,
                                                   const _Float16* __restrict__ Wt,
                                                   const float* __restrict__ a_src,
                                                   const float* __restrict__ a_dst,
                                                   _Float16* __restrict__ Yh,
                                                   float* __restrict__ s,
                                                   float* __restrict__ d, int N) {
    constexpr int FOUT = 64, NT = 4;
    __shared__ _Float16 xs[64][136];
    const int tid  = threadIdx.x;
    const int row0 = blockIdx.x * 64;

    for (int c = tid; c < 1024; c += 256) {            // 64 rows x 16 uint4
        int r = c >> 4, c8 = c & 15;
        uint4 v = make_uint4(0, 0, 0, 0);
        if (row0 + r < N)
            v = reinterpret_cast<const uint4*>(X)[(size_t)(row0 + r) * 16 + c8];
        *reinterpret_cast<uint4*>(&xs[r][c8 * 8]) = v;
    }
    __syncthreads();

    const int wid  = tid >> 6;
    const int lane = tid & 63;
    const int l15  = lane & 15;
    const int lg   = lane >> 4;

    f32x4 acc[NT];
    #pragma unroll
    for (int n = 0; n < NT; ++n) acc[n] = (f32x4){0.f, 0.f, 0.f, 0.f};

    const half8* WtV = reinterpret_cast<const half8*>(Wt);
    #pragma unroll
    for (int ks = 0; ks < 4; ++ks) {
        half8 a = *reinterpret_cast<const half8*>(&xs[wid * 16 + l15][ks * 32 + lg * 8]);
        #pragma unroll
        for (int n = 0; n < NT; ++n) {
            half8 b = WtV[(size_t)(n * 16 + l15) * 16 + ks * 4 + lg];
            acc[n] = __builtin_amdgcn_mfma_f32_16x16x32_f16(a, b, acc[n], 0, 0, 0);
        }
    }

    float av[NT], bv[NT];
    #pragma unroll
    for (int n = 0; n < NT; ++n) {
        av[n] = a_src[n * 16 + l15];
        bv[n] = a_dst[n * 16 + l15];
    }

    #pragma unroll
    for (int r = 0; r < 4; ++r) {
        int row = row0 + wid * 16 + lg * 4 + r;
        bool ok = row < N;
        float ls = 0.f, ld = 0.f;
        #pragma unroll
        for (int n = 0; n < NT; ++n) {
            if (ok) Yh[(size_t)row * FOUT + n * 16 + l15] = (_Float16)acc[n][r];
            ls = fmaf(acc[n][r], av[n], ls);
            ld = fmaf(acc[n][r], bv[n], ld);
        }
        #pragma unroll
        for (int m = 1; m < 16; m <<= 1) {
            ls += __shfl_xor(ls, m);
            ld += __shfl_xor(ld, m);
        }
        if (ok && l15 == 0) {
            s[row] = ls;
            d[row] = ld;
        }
    }
}

__device__ __forceinline__ float edge_w(float x) {
    return __expf(x > 0.f ? x : 0.2f * x);
}

__device__ __forceinline__ void acc8(float* acc, uint4 r, float w) {
    const __half2* h2 = reinterpret_cast<const __half2*>(&r);
    #pragma unroll
    for (int j = 0; j < 4; ++j) {
        float2 f = __half22float2(h2[j]);
        acc[2 * j]     = fmaf(w, f.x, acc[2 * j]);
        acc[2 * j + 1] = fmaf(w, f.y, acc[2 * j + 1]);
    }
}

// Per-dst gather: G = H*C/8 lanes/node, 8 fp16 ch each; 8-deep predicated MLP.
template<int H, int C, bool RELU, bool OUTH>
__global__ __launch_bounds__(256) void gat_gather(const unsigned short* __restrict__ csr,
                                                  const int* __restrict__ row_end,
                                                  const float* __restrict__ s,
                                                  const float* __restrict__ d,
                                                  const _Float16* __restrict__ hh,
                                                  const float* __restrict__ b,
                                                  void* __restrict__ outp, int N) {
    constexpr int CT = H * C;
    constexpr int G  = CT / 8;
    int t = blockIdx.x * blockDim.x + threadIdx.x;
    int node = t / G;
    int lane = t % G;
    if (node >= N) return;

    int start = node ? row_end[node - 1] : 0;
    int end   = row_end[node];

    int c0 = lane * 8;
    int head = c0 / C;
    float dn = d[(size_t)node * H + head];

    float acc[8] = {0.f, 0.f, 0.f, 0.f, 0.f, 0.f, 0.f, 0.f};
    float den = 0.f;

    for (int k = start; k < end; k += 8) {
        int idx[8];
        float sv[8];
        uint4 rr[8];
        #pragma unroll
        for (int j = 0; j < 8; ++j) {
            int kk = k + j;
            int kc = kk < end ? kk : end - 1;
            idx[j] = csr[kc];
            sv[j]  = s[(size_t)idx[j] * H + head];
        }
        #pragma unroll
        for (int j = 0; j < 8; ++j)
            rr[j] = *reinterpret_cast<const uint4*>(&hh[(size_t)idx[j] * CT + c0]);
        #pragma unroll
        for (int j = 0; j < 8; ++j) {
            float w = edge_w(sv[j] + dn);
            if (k + j >= end) w = 0.f;
            den += w;
            acc8(acc, rr[j], w);
        }
    }

    float inv = 1.f / den;
    float o[8];
    #pragma unroll
    for (int j = 0; j < 8; ++j) {
        o[j] = acc[j] * inv + b[c0 + j];
        if (RELU) o[j] = fmaxf(o[j], 0.f);
    }
    if constexpr (OUTH) {
        union { _Float16 h[8]; uint4 u; } pk;
        #pragma unroll
        for (int j = 0; j < 8; ++j) pk.h[j] = (_Float16)o[j];
        _Float16* out = (_Float16*)outp;
        *reinterpret_cast<uint4*>(&out[(size_t)node * CT + c0]) = pk.u;
    } else {
        float* out = (float*)outp;
        float4* op = reinterpret_cast<float4*>(&out[(size_t)node * CT + c0]);
        op[0] = make_float4(o[0], o[1], o[2], o[3]);
        op[1] = make_float4(o[4], o[5], o[6], o[7]);
    }
}

extern "C" void kernel_launch(void* const* d_in, const int* in_sizes, int n_in,
                              void* d_out, int out_size, void* d_ws, size_t ws_size,
                              hipStream_t stream) {
    const float* x      = (const float*)d_in[0];
    const int*   ei     = (const int*)d_in[1];   // [2,E]: [0..E)=src, [E..2E)=dst
    const float* W1     = (const float*)d_in[3];
    const float* a1_src = (const float*)d_in[4];
    const float* a1_dst = (const float*)d_in[5];
    const float* b1     = (const float*)d_in[6];
    const float* W2     = (const float*)d_in[7];
    const float* a2_src = (const float*)d_in[8];
    const float* a2_dst = (const float*)d_in[9];
    const float* b2     = (const float*)d_in[10];

    const int N = in_sizes[0] / 128;        // 50000
    const int E = in_sizes[1] / 2;          // 800000
    const int NB = (N + NTHB - 1) / NTHB;   // 196 buckets
    const int Epb = (E + NBIN - 1) / NBIN;  // 6250 edges per bin block
    const int NG1 = (N + 63) / 64;          // 782 gemm blocks
    float* out = (float*)d_out;

    // workspace layout (float units from f)
    float* f = (float*)d_ws;
    _Float16* h1h = (_Float16*)f;                    // N*128 fp16  [0, 64N)
    _Float16* x2h = (_Float16*)(f + (size_t)N * 64); // N*128 fp16  [64N, 128N)
    unsigned int* packed = (unsigned int*)x2h;       // overlay: NBIN*Epb uints (dead before gather1)
    float* s1 = f + (size_t)N * 128;                 // N*4
    float* d1 = f + (size_t)N * 132;                 // N*4
    int*   row_end = (int*)(f + (size_t)N * 136);    // N
    int*   gtot    = row_end + N;                    // 256
    int*   offs    = gtot + 256;                     // NBIN*(NB+1)
    _Float16* Wt1  = (_Float16*)(offs + NBIN * (NB + 1));  // 128*128 fp16
    _Float16* Wt2  = Wt1 + 128 * 128;                // 64*128 fp16
    unsigned short* csr = (unsigned short*)(Wt2 + 64 * 128);  // E+N
    _Float16* h2h = h1h;                             // overlay, N*64 fp16
    float* s2 = s1;
    float* d2 = d1;

    // 1. weight prep + bucket-total zero
    prep_wt<<<97, 256, 0, stream>>>(W1, W2, Wt1, Wt2, gtot);
    // 2. block-local edge bucket-sort || layer-1 GEMM+scores
    fused_bin_gemm1<<<NBIN + NG1, 256, 0, stream>>>(
        ei, gtot, offs, packed, E, NB, Epb,
        x, Wt1, a1_src, a1_dst, h1h, s1, d1, N);
    // 3. CSR build
    build_csr<<<NB, 256, 0, stream>>>(packed, gtot, offs, csr, row_end, N, NB, Epb);
    // 4. layer-1 gather
    gat_gather<4, 32, true, true><<<(int)(((size_t)N * 16 + 255) / 256), 256, 0, stream>>>(
        csr, row_end, s1, d1, h1h, b1, x2h, N);
    // 5. layer-2 GEMM+scores
    gemm_score2<<<NG1, 256, 0, stream>>>(x2h, Wt2, a2_src, a2_dst, h2h, s2, d2, N);
    // 6. layer-2 gather
    gat_gather<1, 64, false, false><<<(int)(((size_t)N * 8 + 255) / 256), 256, 0, stream>>>(
        csr, row_end, s2, d2, h2h, b2, out, N);
}